// Round 3
// baseline (277.942 us; speedup 1.0000x reference)
//
#include <hip/hip_runtime.h>

// DiceLoss: predict,target fp32 [B=2, O=4, D=64, H=256, W=256]
// out = mean over (b,o) of [ sum_d valid*(1 - 2*num/den) / sum_d valid ]
// num = sum_hw sigmoid(p)*t ; den = sum_hw sigmoid(p) + sum_hw t + 1
// valid = (t[b,o,d,0] != -1)

constexpr int HW     = 256 * 256;                  // 65536 elems per slice
constexpr int NSLICE = 2 * 4 * 64;                 // 512
constexpr int NPAIR  = 2 * 4;                      // 8 (b,o) pairs
constexpr int T      = 256;                        // threads per block
constexpr int CHUNKS_PER_SLICE = 4;
constexpr int NCHUNK = NSLICE * CHUNKS_PER_SLICE;  // 2048 blocks (8/CU)
constexpr int CHUNK_ELEMS = HW / CHUNKS_PER_SLICE; // 16384
constexpr int NITER  = CHUNK_ELEMS / 4 / T;        // 16 float4 per thread per array
constexpr int BATCH  = 4;                          // pipeline stage width

// ws layout (SoA): ws[0..NCHUNK) = sum(p*t), ws[NCHUNK..2N) = sum(p), ws[2N..3N) = sum(t)

__global__ __launch_bounds__(T) void dice_stage1(
    const float* __restrict__ predict,
    const float* __restrict__ target,
    float* __restrict__ ws)
{
    const int chunk = blockIdx.x;
    const int tid   = threadIdx.x;
    const size_t base = (size_t)chunk * CHUNK_ELEMS;
    const float4* __restrict__ p4 = (const float4*)(predict + base);
    const float4* __restrict__ t4 = (const float4*)(target + base);

    float s_pt0 = 0.f, s_pt1 = 0.f, s_p = 0.f, s_t = 0.f;

    // software pipeline: batch k+1 loads are in flight while batch k computes
    float4 pv[BATCH], tv[BATCH];
#pragma unroll
    for (int j = 0; j < BATCH; ++j) {
        pv[j] = p4[j * T + tid];
        tv[j] = t4[j * T + tid];
    }

#pragma unroll
    for (int k0 = 0; k0 < NITER; k0 += BATCH) {
        float4 cp[BATCH], ct[BATCH];
#pragma unroll
        for (int j = 0; j < BATCH; ++j) { cp[j] = pv[j]; ct[j] = tv[j]; }

        if (k0 + BATCH < NITER) {      // static after full unroll
#pragma unroll
            for (int j = 0; j < BATCH; ++j) {
                pv[j] = p4[(k0 + BATCH + j) * T + tid];
                tv[j] = t4[(k0 + BATCH + j) * T + tid];
            }
        }

#pragma unroll
        for (int j = 0; j < BATCH; ++j) {
            float e0 = 1.f / (1.f + __expf(-cp[j].x));
            float e1 = 1.f / (1.f + __expf(-cp[j].y));
            float e2 = 1.f / (1.f + __expf(-cp[j].z));
            float e3 = 1.f / (1.f + __expf(-cp[j].w));
            s_pt0 += e0 * ct[j].x + e1 * ct[j].y;
            s_pt1 += e2 * ct[j].z + e3 * ct[j].w;
            s_p   += (e0 + e1) + (e2 + e3);
            s_t   += (ct[j].x + ct[j].y) + (ct[j].z + ct[j].w);
        }
    }

    float s_pt = s_pt0 + s_pt1;

    // wave (64-lane) reduction, then 4-wave LDS reduction
#pragma unroll
    for (int off = 32; off > 0; off >>= 1) {
        s_pt += __shfl_down(s_pt, off, 64);
        s_p  += __shfl_down(s_p,  off, 64);
        s_t  += __shfl_down(s_t,  off, 64);
    }

    __shared__ float l_pt[T / 64], l_p[T / 64], l_t[T / 64];
    const int wave = tid >> 6;
    const int lane = tid & 63;
    if (lane == 0) { l_pt[wave] = s_pt; l_p[wave] = s_p; l_t[wave] = s_t; }
    __syncthreads();

    if (tid == 0) {
        float a = 0.f, b = 0.f, c = 0.f;
#pragma unroll
        for (int w = 0; w < T / 64; ++w) { a += l_pt[w]; b += l_p[w]; c += l_t[w]; }
        ws[chunk]              = a;
        ws[NCHUNK + chunk]     = b;
        ws[2 * NCHUNK + chunk] = c;
    }
}

__global__ __launch_bounds__(NSLICE) void dice_stage2(
    const float* __restrict__ ws,
    const float* __restrict__ target,
    float* __restrict__ out)
{
    const int s = threadIdx.x;   // slice 0..511; wave w = (b,o) pair (D=64)
    float num = 0.f, sp = 0.f, st = 0.f;
#pragma unroll
    for (int c = 0; c < CHUNKS_PER_SLICE; ++c) {
        const int id = s * CHUNKS_PER_SLICE + c;
        num += ws[id];
        sp  += ws[NCHUNK + id];
        st  += ws[2 * NCHUNK + id];
    }
    float den   = sp + st + 1.0f;                 // SMOOTH = 1
    float dice  = 1.0f - 2.0f * num / den;
    float valid = (target[(size_t)s * HW] != -1.0f) ? 1.0f : 0.0f;

    float dv = dice * valid;
    float v  = valid;
#pragma unroll
    for (int off = 32; off > 0; off >>= 1) {
        dv += __shfl_down(dv, off, 64);
        v  += __shfl_down(v,  off, 64);
    }
    __shared__ float pair_avg[NPAIR];
    const int wave = s >> 6;
    const int lane = s & 63;
    if (lane == 0) pair_avg[wave] = dv / v;
    __syncthreads();
    if (s == 0) {
        float acc = 0.f;
#pragma unroll
        for (int w = 0; w < NPAIR; ++w) acc += pair_avg[w];
        out[0] = acc * (1.0f / NPAIR);
    }
}

extern "C" void kernel_launch(void* const* d_in, const int* in_sizes, int n_in,
                              void* d_out, int out_size, void* d_ws, size_t ws_size,
                              hipStream_t stream) {
    const float* predict = (const float*)d_in[0];
    const float* target  = (const float*)d_in[1];
    float* ws  = (float*)d_ws;
    float* out = (float*)d_out;

    dice_stage1<<<NCHUNK, T, 0, stream>>>(predict, target, ws);
    dice_stage2<<<1, NSLICE, 0, stream>>>(ws, target, out);
}